// Round 6
// baseline (849.967 us; speedup 1.0000x reference)
//
#include <hip/hip_runtime.h>
#include <stdint.h>

#define IC      4096
#define BLK     256
#define WPB     4        // waves per block, one row per wave
#define CHUNKS  16       // float4 chunks per lane per sweep (64 lanes * 64 = 4096)

__global__ __launch_bounds__(BLK, 4) void binarize_kernel(
    const float* __restrict__ x,
    const uint8_t* __restrict__ mask,
    float* __restrict__ out,
    int nrows)
{
    const int lane = threadIdx.x & 63;
    const int row  = blockIdx.x * WPB + (threadIdx.x >> 6);
    if (row >= nrows) return;

    // ---- mask dtype detection (wave-uniform, no LDS/barrier) ----
    const bool mask_is_i32 = !__any(((const uint32_t*)mask)[lane] > 1u);

    const float4* xr4 = (const float4*)(x + (size_t)row * IC);
    float4*       or4 = (float4*)(out + (size_t)row * IC);

    // ---- sweep A: load x + mask ONCE; mask -> 64 bits; s = sum(x*m) [f64 x4] ----
    uint32_t mw0 = 0, mw1 = 0;
    double sacc[4] = {0.0, 0.0, 0.0, 0.0};
    if (mask_is_i32) {
        const int4* mr = (const int4*)mask + (size_t)row * (IC / 4);
        #pragma unroll
        for (int i = 0; i < CHUNKS; ++i) {
            const float4 v  = xr4[lane + 64 * i];
            const int4   m4 = mr[lane + 64 * i];
            const uint32_t b = (uint32_t)(m4.x != 0)
                             | ((uint32_t)(m4.y != 0) << 1)
                             | ((uint32_t)(m4.z != 0) << 2)
                             | ((uint32_t)(m4.w != 0) << 3);
            if (i < 8) mw0 |= b << (4 * i); else mw1 |= b << (4 * (i - 8));
            sacc[0] += (double)((b & 1u) ? v.x : 0.f);
            sacc[1] += (double)((b & 2u) ? v.y : 0.f);
            sacc[2] += (double)((b & 4u) ? v.z : 0.f);
            sacc[3] += (double)((b & 8u) ? v.w : 0.f);
        }
    } else {
        const uint32_t* mr = (const uint32_t*)(mask + (size_t)row * IC);
        #pragma unroll
        for (int i = 0; i < CHUNKS; ++i) {
            const float4   v = xr4[lane + 64 * i];
            const uint32_t w = mr[lane + 64 * i];
            const uint32_t b = (uint32_t)((w & 0x000000ffu) != 0)
                             | ((uint32_t)((w & 0x0000ff00u) != 0) << 1)
                             | ((uint32_t)((w & 0x00ff0000u) != 0) << 2)
                             | ((uint32_t)((w & 0xff000000u) != 0) << 3);
            if (i < 8) mw0 |= b << (4 * i); else mw1 |= b << (4 * (i - 8));
            sacc[0] += (double)((b & 1u) ? v.x : 0.f);
            sacc[1] += (double)((b & 2u) ? v.y : 0.f);
            sacc[2] += (double)((b & 4u) ? v.z : 0.f);
            sacc[3] += (double)((b & 8u) ? v.w : 0.f);
        }
    }
    double s  = (sacc[0] + sacc[1]) + (sacc[2] + sacc[3]);
    float  cf = (float)(__popc(mw0) + __popc(mw1));
    #pragma unroll
    for (int off = 32; off; off >>= 1) {   // wave butterfly, no barrier
        s  += __shfl_xor(s,  off);
        cf += __shfl_xor(cf, off);
    }

    const bool   has    = (cf > 0.f);
    const double c      = (double)cf;
    const double nmiss  = (double)(4096.f - cf);   // # unmasked, exact
    const double inv    = 1.0 / fmax(c, 1.0);
    const double mean1  = has ? s * inv : 0.0;
    const float  mean1f = (float)mean1;

    // ---- sweep B: RELOAD x (L1/L2 hit); sa = sum|x*m - mean1f| over ALL
    // lanes (unmasked contribute exactly |mean1f| -> corrected after);
    // sign from f32 sub (Sterbenz-exact near boundary); d = sum sign1*m. ----
    double saacc[4] = {0.0, 0.0, 0.0, 0.0};
    float  dacc[4]  = {0.f, 0.f, 0.f, 0.f};
    #pragma unroll
    for (int i = 0; i < CHUNKS; ++i) {
        const float4   v = xr4[lane + 64 * i];
        const uint32_t b = ((i < 8) ? (mw0 >> (4 * i)) : (mw1 >> (4 * (i - 8)))) & 0xfu;
        const float xe[4] = { (b & 1u) ? v.x : 0.f, (b & 2u) ? v.y : 0.f,
                              (b & 4u) ? v.z : 0.f, (b & 8u) ? v.w : 0.f };
        #pragma unroll
        for (int k = 0; k < 4; ++k) {
            const float t  = xe[k] - mean1f;
            const float sg = (t > 0.f) ? 1.f : ((t < 0.f) ? -1.f : 0.f);
            dacc[k]  += ((b >> k) & 1u) ? sg : 0.f;
            saacc[k] += (double)fabsf(t);
        }
    }
    double sa = (saacc[0] + saacc[1]) + (saacc[2] + saacc[3]);
    float  df = (dacc[0] + dacc[1]) + (dacc[2] + dacc[3]);
    #pragma unroll
    for (int off = 32; off; off >>= 1) {
        sa += __shfl_xor(sa, off);
        df += __shfl_xor(df, off);
    }
    sa -= nmiss * (double)fabsf(mean1f);   // remove unmasked contributions

    const double scale1 = has ? sa * inv : 0.0;
    // pass C eliminated: sum((x-b1)*m) = s - scale1*d - mean1*c  (b1 = sign1*scale1 + mean1)
    const double mean2  = has ? (s - scale1 * (double)df - mean1 * c) * inv : 0.0;
    const double mean12 = mean1 + mean2;

    // ---- sweep D (f64 element math): scale2 = mean |x - b1 - mean2| over mask.
    // sign1 recomputed identically from reloaded x (same bits -> same value).
    // Unmasked: smv==0 -> t2 == -mean12 exactly -> corrected after. ----
    double sb[4] = {0.0, 0.0, 0.0, 0.0};
    #pragma unroll
    for (int i = 0; i < CHUNKS; ++i) {
        const float4   v = xr4[lane + 64 * i];
        const uint32_t b = ((i < 8) ? (mw0 >> (4 * i)) : (mw1 >> (4 * (i - 8)))) & 0xfu;
        const float xe[4] = { (b & 1u) ? v.x : 0.f, (b & 2u) ? v.y : 0.f,
                              (b & 4u) ? v.z : 0.f, (b & 8u) ? v.w : 0.f };
        #pragma unroll
        for (int k = 0; k < 4; ++k) {
            const float t   = xe[k] - mean1f;
            const float sg  = (t > 0.f) ? 1.f : ((t < 0.f) ? -1.f : 0.f);
            const float smv = ((b >> k) & 1u) ? sg : 0.f;
            const double t2 = (double)xe[k] - fma((double)smv, scale1, mean12);
            sb[k] += fabs(t2);
        }
    }
    double sa2 = (sb[0] + sb[1]) + (sb[2] + sb[3]);
    #pragma unroll
    for (int off = 32; off; off >>= 1) sa2 += __shfl_xor(sa2, off);
    sa2 -= nmiss * fabs(mean12);
    const double scale2  = has ? sa2 * inv : 0.0;
    const float  scale2f = (float)scale2;

    // ---- epilogue sweep (f32): out = (b1 + sign2*scale2 + mean2) * m
    // t2 recomputed identically; b1 + mean2 == x - t2; sign2 from (float)t2
    // (sign-exact). Same numerics class as verified rounds 4/5. ----
    #pragma unroll
    for (int i = 0; i < CHUNKS; ++i) {
        const float4   v = xr4[lane + 64 * i];
        const uint32_t b = ((i < 8) ? (mw0 >> (4 * i)) : (mw1 >> (4 * (i - 8)))) & 0xfu;
        const float xe[4] = { (b & 1u) ? v.x : 0.f, (b & 2u) ? v.y : 0.f,
                              (b & 4u) ? v.z : 0.f, (b & 8u) ? v.w : 0.f };
        float r[4];
        #pragma unroll
        for (int k = 0; k < 4; ++k) {
            const float t   = xe[k] - mean1f;
            const float sg  = (t > 0.f) ? 1.f : ((t < 0.f) ? -1.f : 0.f);
            const float smv = ((b >> k) & 1u) ? sg : 0.f;
            const double t2 = (double)xe[k] - fma((double)smv, scale1, mean12);
            const float t2f = (float)t2;
            const float b1f = xe[k] - t2f;               // b1 + mean2
            const float sg2 = (t2f > 0.f) ? 1.f : ((t2f < 0.f) ? -1.f : 0.f);
            const float o   = fmaf(sg2, scale2f, b1f);
            r[k] = ((b >> k) & 1u) ? o : 0.f;            // unmasked -> exact 0
        }
        float4 o4; o4.x = r[0]; o4.y = r[1]; o4.z = r[2]; o4.w = r[3];
        or4[lane + 64 * i] = o4;
    }
}

extern "C" void kernel_launch(void* const* d_in, const int* in_sizes, int n_in,
                              void* d_out, int out_size, void* d_ws, size_t ws_size,
                              hipStream_t stream) {
    const float*   x    = (const float*)d_in[0];
    const uint8_t* mask = (const uint8_t*)d_in[1];
    float*         out  = (float*)d_out;

    const int rows = in_sizes[0] / IC;        // 11008
    const int grid = (rows + WPB - 1) / WPB;  // 2752
    binarize_kernel<<<grid, BLK, 0, stream>>>(x, mask, out, rows);
}

// Round 8
// 407.311 us; speedup vs baseline: 2.0868x; 2.0868x over previous
//
#include <hip/hip_runtime.h>
#include <stdint.h>

#define IC   4096
#define BLK  256
#define VPT  4          // float4 chunks per thread per row
#define EPT  16         // elements per thread per row

// ---- fused dual-row block reductions (4 waves), results broadcast ----
// Disjoint LDS slots per call -> no trailing barrier needed.
__device__ __forceinline__ void bred_2d2f(double& a, double& b, float& p, float& q,
                                          double* smd, float* smf) {
    #pragma unroll
    for (int off = 32; off; off >>= 1) {
        a += __shfl_xor(a, off);
        b += __shfl_xor(b, off);
        p += __shfl_xor(p, off);
        q += __shfl_xor(q, off);
    }
    const int wid = threadIdx.x >> 6;
    if ((threadIdx.x & 63) == 0) { smd[wid] = a; smd[4 + wid] = b; smf[wid] = p; smf[4 + wid] = q; }
    __syncthreads();
    a = (smd[0] + smd[1]) + (smd[2] + smd[3]);
    b = (smd[4] + smd[5]) + (smd[6] + smd[7]);
    p = (smf[0] + smf[1]) + (smf[2] + smf[3]);
    q = (smf[4] + smf[5]) + (smf[6] + smf[7]);
}

__device__ __forceinline__ void bred_2d(double& a, double& b, double* smd) {
    #pragma unroll
    for (int off = 32; off; off >>= 1) {
        a += __shfl_xor(a, off);
        b += __shfl_xor(b, off);
    }
    const int wid = threadIdx.x >> 6;
    if ((threadIdx.x & 63) == 0) { smd[wid] = a; smd[4 + wid] = b; }
    __syncthreads();
    a = (smd[0] + smd[1]) + (smd[2] + smd[3]);
    b = (smd[4] + smd[5]) + (smd[6] + smd[7]);
}

__global__ __launch_bounds__(BLK) void binarize_kernel(
    const float* __restrict__ x,
    const uint8_t* __restrict__ mask,
    float* __restrict__ out,
    int nrows)
{
    __shared__ double smd[24];
    __shared__ float  smf[16];
    const int tid  = threadIdx.x;
    const int lane = tid & 63;
    const int rowA = (int)blockIdx.x << 1;
    const int rowB = rowA | 1;
    const bool hasB = (rowB < nrows);
    const int rowBs = hasB ? rowB : rowA;   // safe alias for loads

    // ---- mask dtype detection: per-wave __any over first 64 words, no barrier.
    // int32 0/1 mask: every word <= 1. byte mask: P(all 64 words <= 1) = (1/8)^64.
    const bool mask_is_i32 = !__any(((const uint32_t*)mask)[lane] > 1u);

    const float* xrA = x + (size_t)rowA  * IC;
    const float* xrB = x + (size_t)rowBs * IC;

    float xmA[EPT], xmB[EPT];      // x*m, register-resident (HBM read EXACTLY once)
    uint32_t mbA = 0, mbB = 0;     // 16-bit per-thread masks

    #pragma unroll
    for (int i = 0; i < VPT; ++i) {
        const float4 va = ((const float4*)xrA)[tid + i * BLK];
        const float4 vb = ((const float4*)xrB)[tid + i * BLK];
        xmA[i*4+0] = va.x; xmA[i*4+1] = va.y; xmA[i*4+2] = va.z; xmA[i*4+3] = va.w;
        xmB[i*4+0] = vb.x; xmB[i*4+1] = vb.y; xmB[i*4+2] = vb.z; xmB[i*4+3] = vb.w;
    }

    if (mask_is_i32) {
        const int4* mA = (const int4*)mask + (size_t)rowA  * (IC / 4);
        const int4* mB = (const int4*)mask + (size_t)rowBs * (IC / 4);
        #pragma unroll
        for (int i = 0; i < VPT; ++i) {
            const int4 a4 = mA[tid + i * BLK];
            const int4 b4 = mB[tid + i * BLK];
            mbA |= ((uint32_t)(a4.x != 0) | ((uint32_t)(a4.y != 0) << 1)
                 |  ((uint32_t)(a4.z != 0) << 2) | ((uint32_t)(a4.w != 0) << 3)) << (4 * i);
            mbB |= ((uint32_t)(b4.x != 0) | ((uint32_t)(b4.y != 0) << 1)
                 |  ((uint32_t)(b4.z != 0) << 2) | ((uint32_t)(b4.w != 0) << 3)) << (4 * i);
        }
    } else {
        const uint32_t* mA = (const uint32_t*)(mask + (size_t)rowA  * IC);
        const uint32_t* mB = (const uint32_t*)(mask + (size_t)rowBs * IC);
        #pragma unroll
        for (int i = 0; i < VPT; ++i) {
            const uint32_t wa = mA[tid + i * BLK];
            const uint32_t wb = mB[tid + i * BLK];
            mbA |= ((uint32_t)((wa & 0x000000ffu) != 0) | ((uint32_t)((wa & 0x0000ff00u) != 0) << 1)
                 |  ((uint32_t)((wa & 0x00ff0000u) != 0) << 2) | ((uint32_t)((wa & 0xff000000u) != 0) << 3)) << (4 * i);
            mbB |= ((uint32_t)((wb & 0x000000ffu) != 0) | ((uint32_t)((wb & 0x0000ff00u) != 0) << 1)
                 |  ((uint32_t)((wb & 0x00ff0000u) != 0) << 2) | ((uint32_t)((wb & 0xff000000u) != 0) << 3)) << (4 * i);
        }
    }

    #pragma unroll
    for (int j = 0; j < EPT; ++j) {
        xmA[j] = ((mbA >> j) & 1u) ? xmA[j] : 0.f;   // exact masking
        xmB[j] = ((mbB >> j) & 1u) ? xmB[j] : 0.f;
    }

    // ---- pass A: s = sum(x*m) [f64 dual accum], c = popc (exact) ----
    double sA0 = 0.0, sA1 = 0.0, sB0 = 0.0, sB1 = 0.0;
    #pragma unroll
    for (int j = 0; j < EPT; j += 2) {
        sA0 += (double)xmA[j]; sA1 += (double)xmA[j + 1];
        sB0 += (double)xmB[j]; sB1 += (double)xmB[j + 1];
    }
    double sA = sA0 + sA1, sB = sB0 + sB1;
    float cfA = (float)__popc(mbA), cfB = (float)__popc(mbB);
    bred_2d2f(sA, sB, cfA, cfB, smd + 0, smf + 0);   // barrier #1

    const bool   hasA_   = (cfA > 0.f),        hasB_   = (cfB > 0.f);
    const double cA      = (double)cfA,        cB      = (double)cfB;
    const double nmissA  = (double)(4096.f - cfA), nmissB = (double)(4096.f - cfB);
    const double invA    = 1.0 / fmax(cA, 1.0), invB   = 1.0 / fmax(cB, 1.0);
    const double mean1A  = hasA_ ? sA * invA : 0.0, mean1B = hasB_ ? sB * invB : 0.0;
    const float  mean1fA = (float)mean1A,      mean1fB = (float)mean1B;

    // ---- pass B (f32 element math, f64 accumulate): sum|x*m - mean1f| over
    // ALL lanes (unmasked contribute exactly |mean1f| -> corrected after);
    // sign from f32 sub (Sterbenz-exact near boundary); d = sum sign1*m. ----
    double saA0 = 0.0, saA1 = 0.0, saB0 = 0.0, saB1 = 0.0;
    float  dfA = 0.f, dfB = 0.f;
    #pragma unroll
    for (int j = 0; j < EPT; ++j) {
        const float ta = xmA[j] - mean1fA;
        const float sga = (ta > 0.f) ? 1.f : ((ta < 0.f) ? -1.f : 0.f);
        dfA += ((mbA >> j) & 1u) ? sga : 0.f;
        if (j & 1) saA1 += (double)fabsf(ta); else saA0 += (double)fabsf(ta);

        const float tb = xmB[j] - mean1fB;
        const float sgb = (tb > 0.f) ? 1.f : ((tb < 0.f) ? -1.f : 0.f);
        dfB += ((mbB >> j) & 1u) ? sgb : 0.f;
        if (j & 1) saB1 += (double)fabsf(tb); else saB0 += (double)fabsf(tb);
    }
    double saA = saA0 + saA1, saB = saB0 + saB1;
    bred_2d2f(saA, saB, dfA, dfB, smd + 8, smf + 8); // barrier #2
    saA -= nmissA * (double)fabsf(mean1fA);
    saB -= nmissB * (double)fabsf(mean1fB);

    const double scale1A = hasA_ ? saA * invA : 0.0, scale1B = hasB_ ? saB * invB : 0.0;
    // pass C eliminated: sum((x-b1)*m) = s - scale1*d - mean1*c
    const double mean2A  = hasA_ ? (sA - scale1A * (double)dfA - mean1A * cA) * invA : 0.0;
    const double mean2B  = hasB_ ? (sB - scale1B * (double)dfB - mean1B * cB) * invB : 0.0;
    const double mean12A = mean1A + mean2A, mean12B = mean1B + mean2B;

    // ---- pass D (f64): scale2 = mean |x - b1 - mean2| over mask.
    // sign1 recomputed identically; unmasked: t2 == -mean12 exactly -> corrected. ----
    double s2A0 = 0.0, s2A1 = 0.0, s2B0 = 0.0, s2B1 = 0.0;
    #pragma unroll
    for (int j = 0; j < EPT; ++j) {
        const float ta = xmA[j] - mean1fA;
        const float sga = (ta > 0.f) ? 1.f : ((ta < 0.f) ? -1.f : 0.f);
        const float sva = ((mbA >> j) & 1u) ? sga : 0.f;
        const double t2a = (double)xmA[j] - fma((double)sva, scale1A, mean12A);
        if (j & 1) s2A1 += fabs(t2a); else s2A0 += fabs(t2a);

        const float tb = xmB[j] - mean1fB;
        const float sgb = (tb > 0.f) ? 1.f : ((tb < 0.f) ? -1.f : 0.f);
        const float svb = ((mbB >> j) & 1u) ? sgb : 0.f;
        const double t2b = (double)xmB[j] - fma((double)svb, scale1B, mean12B);
        if (j & 1) s2B1 += fabs(t2b); else s2B0 += fabs(t2b);
    }
    double sa2A = s2A0 + s2A1, sa2B = s2B0 + s2B1;
    bred_2d(sa2A, sa2B, smd + 16);                   // barrier #3
    sa2A -= nmissA * fabs(mean12A);
    sa2B -= nmissB * fabs(mean12B);
    const double scale2A  = hasA_ ? sa2A * invA : 0.0, scale2B = hasB_ ? sa2B * invB : 0.0;
    const float  scale2fA = (float)scale2A,            scale2fB = (float)scale2B;

    // ---- epilogue (f32): out = (b1 + sign2*scale2 + mean2)*m; t2 recomputed
    // identically; b1+mean2 == x - t2; sign2 from (float)t2 (sign-exact). ----
    float* orA = out + (size_t)rowA * IC;
    float* orB = out + (size_t)rowB * IC;   // only stored if hasB
    #pragma unroll
    for (int i = 0; i < VPT; ++i) {
        float ra[4], rb[4];
        #pragma unroll
        for (int k = 0; k < 4; ++k) {
            const int j = 4 * i + k;
            {
                const float ta = xmA[j] - mean1fA;
                const float sga = (ta > 0.f) ? 1.f : ((ta < 0.f) ? -1.f : 0.f);
                const float sva = ((mbA >> j) & 1u) ? sga : 0.f;
                const double t2 = (double)xmA[j] - fma((double)sva, scale1A, mean12A);
                const float t2f = (float)t2;
                const float b1f = xmA[j] - t2f;
                const float sg2 = (t2f > 0.f) ? 1.f : ((t2f < 0.f) ? -1.f : 0.f);
                ra[k] = ((mbA >> j) & 1u) ? fmaf(sg2, scale2fA, b1f) : 0.f;
            }
            {
                const float tb = xmB[j] - mean1fB;
                const float sgb = (tb > 0.f) ? 1.f : ((tb < 0.f) ? -1.f : 0.f);
                const float svb = ((mbB >> j) & 1u) ? sgb : 0.f;
                const double t2 = (double)xmB[j] - fma((double)svb, scale1B, mean12B);
                const float t2f = (float)t2;
                const float b1f = xmB[j] - t2f;
                const float sg2 = (t2f > 0.f) ? 1.f : ((t2f < 0.f) ? -1.f : 0.f);
                rb[k] = ((mbB >> j) & 1u) ? fmaf(sg2, scale2fB, b1f) : 0.f;
            }
        }
        float4 oa; oa.x = ra[0]; oa.y = ra[1]; oa.z = ra[2]; oa.w = ra[3];
        ((float4*)orA)[tid + i * BLK] = oa;
        if (hasB) {
            float4 ob; ob.x = rb[0]; ob.y = rb[1]; ob.z = rb[2]; ob.w = rb[3];
            ((float4*)orB)[tid + i * BLK] = ob;
        }
    }
}

extern "C" void kernel_launch(void* const* d_in, const int* in_sizes, int n_in,
                              void* d_out, int out_size, void* d_ws, size_t ws_size,
                              hipStream_t stream) {
    const float*   x    = (const float*)d_in[0];
    const uint8_t* mask = (const uint8_t*)d_in[1];
    float*         out  = (float*)d_out;

    const int rows = in_sizes[0] / IC;      // 11008
    const int grid = (rows + 1) / 2;        // 5504 blocks, 2 rows each
    binarize_kernel<<<grid, BLK, 0, stream>>>(x, mask, out, rows);
}